// Round 1
// baseline (20745.845 us; speedup 1.0000x reference)
//
#include <hip/hip_runtime.h>
#include <hip/hip_bf16.h>

#define T_STEPS 1024
// ws layout (float offsets)
#define OFF_AFT   0ull
#define OFF_GCAT  4194304ull
#define OFF_CFT   8388608ull
#define OFF_DELTA 10485760ull
#define OFF_BX    27262976ull
#define OFF_HS    44040192ull
#define OFF_HBUF  60817408ull
#define OFF_FLAGS 60850176ull

__device__ __forceinline__ void build_oct_tables(int tid, int (*Is)[8], float (*Sg)[8]) {
  if (tid < 64) {
    int i = tid >> 3, j = tid & 7;
    int k = 0; float s = 0.f;
    if (i == 0)      { k = j; s = 1.f; }
    else if (j == 0) { k = i; s = 1.f; }
    else if (i == j) { k = 0; s = -1.f; }
    else {
      const int T7[7][3] = {{1,2,4},{2,3,5},{3,4,6},{4,5,7},{5,6,1},{6,7,2},{7,1,3}};
      for (int t = 0; t < 7; ++t) {
        int a = T7[t][0], b = T7[t][1], c = T7[t][2];
        const int P[3][3] = {{a,b,c},{b,c,a},{c,a,b}};
        for (int r = 0; r < 3; ++r) {
          if (i == P[r][0] && j == P[r][1]) { k = P[r][2]; s = 1.f; }
          if (i == P[r][1] && j == P[r][0]) { k = P[r][2]; s = -1.f; }
        }
      }
    }
    Is[j][k] = i; Sg[j][k] = s;
  }
  __syncthreads();
}

// AfT_blocked[blk=sp>>3][s][c=sp&7] = Af[sp][s],  Af[k*256+o][j*256+n] = Sg[j][k]*WA[i][o][n]
__global__ __launch_bounds__(256) void fold_A(const float* __restrict__ WA, float* __restrict__ AfT) {
  __shared__ int Is[8][8]; __shared__ float Sg[8][8];
  build_oct_tables(threadIdx.x, Is, Sg);
  int g4 = blockIdx.x * 256 + threadIdx.x;   // 0..1048575
  int c4  = (g4 & 1) * 4;
  int s   = (g4 >> 1) & 2047;
  int blk = g4 >> 12;
  int j = s >> 8, n = s & 255;
  int spbase = blk * 8 + c4;
  int k = spbase >> 8;
  int i = Is[j][k]; float sg = Sg[j][k];
  const float* wa = WA + (size_t)i * 65536 + n;
  float4 v;
  v.x = sg * wa[(size_t)((spbase + 0) & 255) * 256];
  v.y = sg * wa[(size_t)((spbase + 1) & 255) * 256];
  v.z = sg * wa[(size_t)((spbase + 2) & 255) * 256];
  v.w = sg * wa[(size_t)((spbase + 3) & 255) * 256];
  *(float4*)(AfT + (size_t)g4 * 4) = v;
}

// Gcat[d][0..2047] = Wdelta[s][d],  Gcat[d][2048+sp] = Bf[sp][d] = Sg[j][k]*WB[i][o][n]
__global__ __launch_bounds__(256) void fold_GC(const float* __restrict__ Wd, const float* __restrict__ WB,
                                               float* __restrict__ Gcat) {
  __shared__ int Is[8][8]; __shared__ float Sg[8][8];
  build_oct_tables(threadIdx.x, Is, Sg);
  int g4 = blockIdx.x * 256 + threadIdx.x;   // 0..1048575 (1024 rows x 1024 float4)
  int col = (g4 & 1023) * 4;
  int d = g4 >> 10;
  float4 v;
  if (col < 2048) {
    v.x = Wd[(size_t)(col + 0) * 1024 + d];
    v.y = Wd[(size_t)(col + 1) * 1024 + d];
    v.z = Wd[(size_t)(col + 2) * 1024 + d];
    v.w = Wd[(size_t)(col + 3) * 1024 + d];
  } else {
    int sp = col - 2048;
    int k = sp >> 8;
    int j = d >> 7, n = d & 127;
    int i = Is[j][k]; float sg = Sg[j][k];
    const float* wb = WB + (size_t)i * 32768 + n;
    v.x = sg * wb[(size_t)((sp + 0) & 255) * 128];
    v.y = sg * wb[(size_t)((sp + 1) & 255) * 128];
    v.z = sg * wb[(size_t)((sp + 2) & 255) * 128];
    v.w = sg * wb[(size_t)((sp + 3) & 255) * 128];
  }
  *(float4*)(Gcat + (size_t)g4 * 4) = v;
}

// CfT[s][d] = Cf[d][s] = Sg[j][k]*WC[i][o][n]  (d=k*128+o, s=j*256+n)
__global__ __launch_bounds__(256) void fold_C(const float* __restrict__ WC, float* __restrict__ CfT) {
  __shared__ int Is[8][8]; __shared__ float Sg[8][8];
  build_oct_tables(threadIdx.x, Is, Sg);
  int g4 = blockIdx.x * 256 + threadIdx.x;   // 0..524287 (2048 rows x 256 float4)
  int d0 = (g4 & 255) * 4;
  int s  = g4 >> 8;
  int j = s >> 8, n = s & 255;
  int k = d0 >> 7;
  int i = Is[j][k]; float sg = Sg[j][k];
  const float* wc = WC + (size_t)i * 32768 + n;
  float4 v;
  v.x = sg * wc[(size_t)((d0 + 0) & 127) * 256];
  v.y = sg * wc[(size_t)((d0 + 1) & 127) * 256];
  v.z = sg * wc[(size_t)((d0 + 2) & 127) * 256];
  v.w = sg * wc[(size_t)((d0 + 3) & 127) * 256];
  *(float4*)(CfT + (size_t)g4 * 4) = v;
}

__global__ __launch_bounds__(256) void init_h(const float* __restrict__ h_prev, float* __restrict__ hbuf,
                                              int* __restrict__ flags) {
  int gid = blockIdx.x * 256 + threadIdx.x;  // 0..16383, layout [s][b]
  int s = gid >> 3, b = gid & 7;
  hbuf[gid] = h_prev[(size_t)b * 2048 + s];
  if (blockIdx.x == 0) flags[threadIdx.x] = 0;
}

// C = X[8192x1024] * Gcat[1024x4096]; cols<2048 -> sigmoid(+bias) -> delta[t][b][s]; else Bx[t][b][s]
__global__ __launch_bounds__(256) void gemm_dbx(const float* __restrict__ X, const float* __restrict__ G,
                                                const float* __restrict__ bias,
                                                float* __restrict__ dlt, float* __restrict__ Bx) {
  __shared__ float As[16][128];
  __shared__ float Bs[16][128];
  const int bn = blockIdx.x, bm = blockIdx.y;
  const int tid = threadIdx.x;
  const int tx = tid & 15, ty = tid >> 4;
  float acc[8][8] = {};
  for (int kt = 0; kt < 1024; kt += 16) {
    #pragma unroll
    for (int q = 0; q < 2; ++q) {
      int slot = tid * 2 + q;
      int r = slot >> 2, c4 = slot & 3;
      float4 v = *(const float4*)(X + (size_t)(bm * 128 + r) * 1024 + kt + c4 * 4);
      As[c4 * 4 + 0][r] = v.x; As[c4 * 4 + 1][r] = v.y;
      As[c4 * 4 + 2][r] = v.z; As[c4 * 4 + 3][r] = v.w;
    }
    #pragma unroll
    for (int q = 0; q < 2; ++q) {
      int slot = tid * 2 + q;
      int kr = slot >> 5, c4 = slot & 31;
      *(float4*)(&Bs[kr][c4 * 4]) = *(const float4*)(G + (size_t)(kt + kr) * 4096 + bn * 128 + c4 * 4);
    }
    __syncthreads();
    #pragma unroll
    for (int kk = 0; kk < 16; ++kk) {
      float a[8], b[8];
      #pragma unroll
      for (int i = 0; i < 8; ++i) a[i] = As[kk][ty + i * 16];
      #pragma unroll
      for (int j = 0; j < 8; ++j) b[j] = Bs[kk][tx + j * 16];
      #pragma unroll
      for (int i = 0; i < 8; ++i)
        #pragma unroll
        for (int j = 0; j < 8; ++j)
          acc[i][j] = fmaf(a[i], b[j], acc[i][j]);
    }
    __syncthreads();
  }
  const bool isDelta = (bn < 16);
  #pragma unroll
  for (int i = 0; i < 8; ++i) {
    int r = bm * 128 + ty + i * 16;
    int t = r & 1023, b = r >> 10;
    size_t base = ((size_t)t * 8 + b) * 2048;
    #pragma unroll
    for (int j = 0; j < 8; ++j) {
      int n = bn * 128 + tx + j * 16;
      float v = acc[i][j];
      if (isDelta) {
        v += bias[n];
        v = 1.0f / (1.0f + expf(-v));
        dlt[base + n] = v;
      } else {
        Bx[base + (n - 2048)] = v;
      }
    }
  }
}

// y[b][t][d] = sum_s hs[t*8+b][s] * CfT[s][d]
__global__ __launch_bounds__(256) void gemm_y(const float* __restrict__ HS, const float* __restrict__ CfT,
                                              float* __restrict__ out) {
  __shared__ float As[16][128];
  __shared__ float Bs[16][128];
  const int bn = blockIdx.x, bm = blockIdx.y;
  const int tid = threadIdx.x;
  const int tx = tid & 15, ty = tid >> 4;
  float acc[8][8] = {};
  for (int kt = 0; kt < 2048; kt += 16) {
    #pragma unroll
    for (int q = 0; q < 2; ++q) {
      int slot = tid * 2 + q;
      int r = slot >> 2, c4 = slot & 3;
      int rg = bm * 128 + r;
      const float* arow = HS + (size_t)((rg & 1023) * 8 + (rg >> 10)) * 2048;
      float4 v = *(const float4*)(arow + kt + c4 * 4);
      As[c4 * 4 + 0][r] = v.x; As[c4 * 4 + 1][r] = v.y;
      As[c4 * 4 + 2][r] = v.z; As[c4 * 4 + 3][r] = v.w;
    }
    #pragma unroll
    for (int q = 0; q < 2; ++q) {
      int slot = tid * 2 + q;
      int kr = slot >> 5, c4 = slot & 31;
      *(float4*)(&Bs[kr][c4 * 4]) = *(const float4*)(CfT + (size_t)(kt + kr) * 1024 + bn * 128 + c4 * 4);
    }
    __syncthreads();
    #pragma unroll
    for (int kk = 0; kk < 16; ++kk) {
      float a[8], b[8];
      #pragma unroll
      for (int i = 0; i < 8; ++i) a[i] = As[kk][ty + i * 16];
      #pragma unroll
      for (int j = 0; j < 8; ++j) b[j] = Bs[kk][tx + j * 16];
      #pragma unroll
      for (int i = 0; i < 8; ++i)
        #pragma unroll
        for (int j = 0; j < 8; ++j)
          acc[i][j] = fmaf(a[i], b[j], acc[i][j]);
    }
    __syncthreads();
  }
  #pragma unroll
  for (int i = 0; i < 8; ++i) {
    size_t rg = bm * 128 + ty + i * 16;
    #pragma unroll
    for (int j = 0; j < 8; ++j) {
      int n = bn * 128 + tx + j * 16;
      out[rg * 1024 + n] = acc[i][j];
    }
  }
}

// Persistent sequential scan: 256 WGs x 512 threads. WG owns 8 state columns; AfT slice resident in LDS.
__global__ __launch_bounds__(512) void scan_kernel(const float* __restrict__ AfT, const float* __restrict__ dlt,
                                                   const float* __restrict__ Bx, float* __restrict__ hs,
                                                   float* __restrict__ hbuf, int* __restrict__ flags,
                                                   float* __restrict__ hlast) {
  __shared__ __attribute__((aligned(16))) float smem[16384 + 512];  // Af [2048][8] + red [8][64]
  float* red = smem + 16384;
  const int wg = blockIdx.x;
  const int tid = threadIdx.x;
  const int lane = tid & 63;
  const int w = tid >> 6;            // 0..7 (wave)
  const int b = lane & 7, sg = lane >> 3;

  {
    const float* src = AfT + (size_t)wg * 16384;
    #pragma unroll
    for (int q = 0; q < 8; ++q) {
      int i4 = q * 512 + tid;
      *(float4*)(&smem[i4 * 4]) = *(const float4*)(src + (size_t)i4 * 4);
    }
  }
  __syncthreads();

  #pragma unroll 1
  for (int t = 0; t < T_STEPS; ++t) {
    const float* hcur = hbuf + (size_t)(t & 1) * 16384;   // [s][b]
    const float* hp = hcur + w * 2048 + lane;
    float acc0 = 0.f, acc1 = 0.f, acc2 = 0.f, acc3 = 0.f;
    float acc4 = 0.f, acc5 = 0.f, acc6 = 0.f, acc7 = 0.f;
    const int sbase = w * 256 + sg;                        // s = sbase + i*8
    #pragma unroll 8
    for (int i = 0; i < 32; ++i) {
      float hv = hp[(size_t)i * 64];
      int off = (sbase + i * 8) * 8;
      float4 a0 = *(const float4*)(&smem[off]);
      float4 a1 = *(const float4*)(&smem[off + 4]);
      acc0 = fmaf(a0.x, hv, acc0); acc1 = fmaf(a0.y, hv, acc1);
      acc2 = fmaf(a0.z, hv, acc2); acc3 = fmaf(a0.w, hv, acc3);
      acc4 = fmaf(a1.x, hv, acc4); acc5 = fmaf(a1.y, hv, acc5);
      acc6 = fmaf(a1.z, hv, acc6); acc7 = fmaf(a1.w, hv, acc7);
    }
    #pragma unroll
    for (int m = 8; m < 64; m <<= 1) {
      acc0 += __shfl_xor(acc0, m, 64); acc1 += __shfl_xor(acc1, m, 64);
      acc2 += __shfl_xor(acc2, m, 64); acc3 += __shfl_xor(acc3, m, 64);
      acc4 += __shfl_xor(acc4, m, 64); acc5 += __shfl_xor(acc5, m, 64);
      acc6 += __shfl_xor(acc6, m, 64); acc7 += __shfl_xor(acc7, m, 64);
    }
    if (sg == 0) {
      float* r = red + w * 64 + b * 8;
      r[0] = acc0; r[1] = acc1; r[2] = acc2; r[3] = acc3;
      r[4] = acc4; r[5] = acc5; r[6] = acc6; r[7] = acc7;
    }
    __syncthreads();
    if (tid < 64) {
      float outv = red[tid] + red[64 + tid] + red[128 + tid] + red[192 + tid]
                 + red[256 + tid] + red[320 + tid] + red[384 + tid] + red[448 + tid];
      int bb = tid >> 3, cc = tid & 7;
      int sp = wg * 8 + cc;
      size_t row = (size_t)t * 8 + bb;
      float dv = dlt[row * 2048 + sp];
      float bx = Bx[row * 2048 + sp];
      float hold = hcur[sp * 8 + bb];
      float hn = fmaf(dv, outv + bx - hold, hold);
      hs[row * 2048 + sp] = hn;
      hbuf[(size_t)((t + 1) & 1) * 16384 + sp * 8 + bb] = hn;
      if (t == T_STEPS - 1) hlast[(size_t)bb * 2048 + sp] = hn;
    }
    __syncthreads();   // all slice stores drained (vmcnt) before flag
    if (tid == 0) {
      __threadfence();  // release: write back L2 so other XCDs see the slice
      __hip_atomic_store(&flags[wg], t + 1, __ATOMIC_RELEASE, __HIP_MEMORY_SCOPE_AGENT);
    }
    if (w == 0) {
      for (;;) {
        int f0 = __hip_atomic_load(&flags[lane],       __ATOMIC_RELAXED, __HIP_MEMORY_SCOPE_AGENT);
        int f1 = __hip_atomic_load(&flags[lane + 64],  __ATOMIC_RELAXED, __HIP_MEMORY_SCOPE_AGENT);
        int f2 = __hip_atomic_load(&flags[lane + 128], __ATOMIC_RELAXED, __HIP_MEMORY_SCOPE_AGENT);
        int f3 = __hip_atomic_load(&flags[lane + 192], __ATOMIC_RELAXED, __HIP_MEMORY_SCOPE_AGENT);
        int ok = (f0 > t) && (f1 > t) && (f2 > t) && (f3 > t);
        if (__all(ok)) break;
        __builtin_amdgcn_s_sleep(2);
      }
      __threadfence();  // acquire: invalidate L1/L2 so next h loads are fresh
    }
    __syncthreads();
  }
}

extern "C" void kernel_launch(void* const* d_in, const int* in_sizes, int n_in,
                              void* d_out, int out_size, void* d_ws, size_t ws_size,
                              hipStream_t stream) {
  const float* x      = (const float*)d_in[0];
  const float* h_prev = (const float*)d_in[1];
  const float* WA     = (const float*)d_in[2];
  const float* WB     = (const float*)d_in[3];
  const float* WC     = (const float*)d_in[4];
  const float* Wd     = (const float*)d_in[5];
  const float* bias   = (const float*)d_in[6];
  float* out = (float*)d_out;
  float* w = (float*)d_ws;
  float* AfT  = w + OFF_AFT;
  float* Gcat = w + OFF_GCAT;
  float* CfT  = w + OFF_CFT;
  float* dlt  = w + OFF_DELTA;
  float* Bx   = w + OFF_BX;
  float* hs   = w + OFF_HS;
  float* hbuf = w + OFF_HBUF;
  int*   flags = (int*)(w + OFF_FLAGS);

  fold_A <<<4096, 256, 0, stream>>>(WA, AfT);
  fold_GC<<<4096, 256, 0, stream>>>(Wd, WB, Gcat);
  fold_C <<<2048, 256, 0, stream>>>(WC, CfT);
  init_h <<<64,   256, 0, stream>>>(h_prev, hbuf, flags);
  gemm_dbx<<<dim3(32, 64), 256, 0, stream>>>(x, Gcat, bias, dlt, Bx);
  scan_kernel<<<256, 512, 0, stream>>>(AfT, dlt, Bx, hs, hbuf, flags, out + 8388608);
  gemm_y<<<dim3(8, 64), 256, 0, stream>>>(hs, CfT, out);
}

// Round 2
// 8999.092 us; speedup vs baseline: 2.3053x; 2.3053x over previous
//
#include <hip/hip_runtime.h>
#include <hip/hip_bf16.h>

#define T_STEPS 1024
// ws layout (float offsets)
#define OFF_AFT   0ull
#define OFF_GCAT  4194304ull
#define OFF_CFT   8388608ull
#define OFF_DELTA 10485760ull
#define OFF_BX    27262976ull
#define OFF_HS    44040192ull
#define OFF_HBUF  60817408ull
#define OFF_FLAGS 60850176ull

__device__ __forceinline__ void build_oct_tables(int tid, int (*Is)[8], float (*Sg)[8]) {
  if (tid < 64) {
    int i = tid >> 3, j = tid & 7;
    int k = 0; float s = 0.f;
    if (i == 0)      { k = j; s = 1.f; }
    else if (j == 0) { k = i; s = 1.f; }
    else if (i == j) { k = 0; s = -1.f; }
    else {
      const int T7[7][3] = {{1,2,4},{2,3,5},{3,4,6},{4,5,7},{5,6,1},{6,7,2},{7,1,3}};
      for (int t = 0; t < 7; ++t) {
        int a = T7[t][0], b = T7[t][1], c = T7[t][2];
        const int P[3][3] = {{a,b,c},{b,c,a},{c,a,b}};
        for (int r = 0; r < 3; ++r) {
          if (i == P[r][0] && j == P[r][1]) { k = P[r][2]; s = 1.f; }
          if (i == P[r][1] && j == P[r][0]) { k = P[r][2]; s = -1.f; }
        }
      }
    }
    Is[j][k] = i; Sg[j][k] = s;
  }
  __syncthreads();
}

// AfT_blocked[blk=sp>>3][s][c=sp&7] = Af[sp][s],  Af[k*256+o][j*256+n] = Sg[j][k]*WA[i][o][n]
__global__ __launch_bounds__(256) void fold_A(const float* __restrict__ WA, float* __restrict__ AfT) {
  __shared__ int Is[8][8]; __shared__ float Sg[8][8];
  build_oct_tables(threadIdx.x, Is, Sg);
  int g4 = blockIdx.x * 256 + threadIdx.x;   // 0..1048575
  int c4  = (g4 & 1) * 4;
  int s   = (g4 >> 1) & 2047;
  int blk = g4 >> 12;
  int j = s >> 8, n = s & 255;
  int spbase = blk * 8 + c4;
  int k = spbase >> 8;
  int i = Is[j][k]; float sg = Sg[j][k];
  const float* wa = WA + (size_t)i * 65536 + n;
  float4 v;
  v.x = sg * wa[(size_t)((spbase + 0) & 255) * 256];
  v.y = sg * wa[(size_t)((spbase + 1) & 255) * 256];
  v.z = sg * wa[(size_t)((spbase + 2) & 255) * 256];
  v.w = sg * wa[(size_t)((spbase + 3) & 255) * 256];
  *(float4*)(AfT + (size_t)g4 * 4) = v;
}

// Gcat[d][0..2047] = Wdelta[s][d],  Gcat[d][2048+sp] = Bf[sp][d] = Sg[j][k]*WB[i][o][n]
__global__ __launch_bounds__(256) void fold_GC(const float* __restrict__ Wd, const float* __restrict__ WB,
                                               float* __restrict__ Gcat) {
  __shared__ int Is[8][8]; __shared__ float Sg[8][8];
  build_oct_tables(threadIdx.x, Is, Sg);
  int g4 = blockIdx.x * 256 + threadIdx.x;   // 0..1048575 (1024 rows x 1024 float4)
  int col = (g4 & 1023) * 4;
  int d = g4 >> 10;
  float4 v;
  if (col < 2048) {
    v.x = Wd[(size_t)(col + 0) * 1024 + d];
    v.y = Wd[(size_t)(col + 1) * 1024 + d];
    v.z = Wd[(size_t)(col + 2) * 1024 + d];
    v.w = Wd[(size_t)(col + 3) * 1024 + d];
  } else {
    int sp = col - 2048;
    int k = sp >> 8;
    int j = d >> 7, n = d & 127;
    int i = Is[j][k]; float sg = Sg[j][k];
    const float* wb = WB + (size_t)i * 32768 + n;
    v.x = sg * wb[(size_t)((sp + 0) & 255) * 128];
    v.y = sg * wb[(size_t)((sp + 1) & 255) * 128];
    v.z = sg * wb[(size_t)((sp + 2) & 255) * 128];
    v.w = sg * wb[(size_t)((sp + 3) & 255) * 128];
  }
  *(float4*)(Gcat + (size_t)g4 * 4) = v;
}

// CfT[s][d] = Cf[d][s] = Sg[j][k]*WC[i][o][n]  (d=k*128+o, s=j*256+n)
__global__ __launch_bounds__(256) void fold_C(const float* __restrict__ WC, float* __restrict__ CfT) {
  __shared__ int Is[8][8]; __shared__ float Sg[8][8];
  build_oct_tables(threadIdx.x, Is, Sg);
  int g4 = blockIdx.x * 256 + threadIdx.x;   // 0..524287 (2048 rows x 256 float4)
  int d0 = (g4 & 255) * 4;
  int s  = g4 >> 8;
  int j = s >> 8, n = s & 255;
  int k = d0 >> 7;
  int i = Is[j][k]; float sg = Sg[j][k];
  const float* wc = WC + (size_t)i * 32768 + n;
  float4 v;
  v.x = sg * wc[(size_t)((d0 + 0) & 127) * 256];
  v.y = sg * wc[(size_t)((d0 + 1) & 127) * 256];
  v.z = sg * wc[(size_t)((d0 + 2) & 127) * 256];
  v.w = sg * wc[(size_t)((d0 + 3) & 127) * 256];
  *(float4*)(CfT + (size_t)g4 * 4) = v;
}

// hbuf layout is [b][s] (same as h_prev) -> plain copy
__global__ __launch_bounds__(256) void init_h(const float* __restrict__ h_prev, float* __restrict__ hbuf,
                                              int* __restrict__ flags) {
  int gid = blockIdx.x * 256 + threadIdx.x;  // 0..16383
  hbuf[gid] = h_prev[gid];
  if (blockIdx.x == 0) flags[threadIdx.x] = 0;
}

// C = X[8192x1024] * Gcat[1024x4096]; cols<2048 -> sigmoid(+bias) -> delta[t][b][s]; else Bx[t][b][s]
__global__ __launch_bounds__(256) void gemm_dbx(const float* __restrict__ X, const float* __restrict__ G,
                                                const float* __restrict__ bias,
                                                float* __restrict__ dlt, float* __restrict__ Bx) {
  __shared__ float As[16][128];
  __shared__ float Bs[16][128];
  const int bn = blockIdx.x, bm = blockIdx.y;
  const int tid = threadIdx.x;
  const int tx = tid & 15, ty = tid >> 4;
  float acc[8][8] = {};
  for (int kt = 0; kt < 1024; kt += 16) {
    #pragma unroll
    for (int q = 0; q < 2; ++q) {
      int slot = tid * 2 + q;
      int r = slot >> 2, c4 = slot & 3;
      float4 v = *(const float4*)(X + (size_t)(bm * 128 + r) * 1024 + kt + c4 * 4);
      As[c4 * 4 + 0][r] = v.x; As[c4 * 4 + 1][r] = v.y;
      As[c4 * 4 + 2][r] = v.z; As[c4 * 4 + 3][r] = v.w;
    }
    #pragma unroll
    for (int q = 0; q < 2; ++q) {
      int slot = tid * 2 + q;
      int kr = slot >> 5, c4 = slot & 31;
      *(float4*)(&Bs[kr][c4 * 4]) = *(const float4*)(G + (size_t)(kt + kr) * 4096 + bn * 128 + c4 * 4);
    }
    __syncthreads();
    #pragma unroll
    for (int kk = 0; kk < 16; ++kk) {
      float a[8], b[8];
      #pragma unroll
      for (int i = 0; i < 8; ++i) a[i] = As[kk][ty + i * 16];
      #pragma unroll
      for (int j = 0; j < 8; ++j) b[j] = Bs[kk][tx + j * 16];
      #pragma unroll
      for (int i = 0; i < 8; ++i)
        #pragma unroll
        for (int j = 0; j < 8; ++j)
          acc[i][j] = fmaf(a[i], b[j], acc[i][j]);
    }
    __syncthreads();
  }
  const bool isDelta = (bn < 16);
  #pragma unroll
  for (int i = 0; i < 8; ++i) {
    int r = bm * 128 + ty + i * 16;
    int t = r & 1023, b = r >> 10;
    size_t base = ((size_t)t * 8 + b) * 2048;
    #pragma unroll
    for (int j = 0; j < 8; ++j) {
      int n = bn * 128 + tx + j * 16;
      float v = acc[i][j];
      if (isDelta) {
        v += bias[n];
        v = 1.0f / (1.0f + expf(-v));
        dlt[base + n] = v;
      } else {
        Bx[base + (n - 2048)] = v;
      }
    }
  }
}

// y[b][t][d] = sum_s hs[t*8+b][s] * CfT[s][d]
__global__ __launch_bounds__(256) void gemm_y(const float* __restrict__ HS, const float* __restrict__ CfT,
                                              float* __restrict__ out) {
  __shared__ float As[16][128];
  __shared__ float Bs[16][128];
  const int bn = blockIdx.x, bm = blockIdx.y;
  const int tid = threadIdx.x;
  const int tx = tid & 15, ty = tid >> 4;
  float acc[8][8] = {};
  for (int kt = 0; kt < 2048; kt += 16) {
    #pragma unroll
    for (int q = 0; q < 2; ++q) {
      int slot = tid * 2 + q;
      int r = slot >> 2, c4 = slot & 3;
      int rg = bm * 128 + r;
      const float* arow = HS + (size_t)((rg & 1023) * 8 + (rg >> 10)) * 2048;
      float4 v = *(const float4*)(arow + kt + c4 * 4);
      As[c4 * 4 + 0][r] = v.x; As[c4 * 4 + 1][r] = v.y;
      As[c4 * 4 + 2][r] = v.z; As[c4 * 4 + 3][r] = v.w;
    }
    #pragma unroll
    for (int q = 0; q < 2; ++q) {
      int slot = tid * 2 + q;
      int kr = slot >> 5, c4 = slot & 31;
      *(float4*)(&Bs[kr][c4 * 4]) = *(const float4*)(CfT + (size_t)(kt + kr) * 1024 + bn * 128 + c4 * 4);
    }
    __syncthreads();
    #pragma unroll
    for (int kk = 0; kk < 16; ++kk) {
      float a[8], b[8];
      #pragma unroll
      for (int i = 0; i < 8; ++i) a[i] = As[kk][ty + i * 16];
      #pragma unroll
      for (int j = 0; j < 8; ++j) b[j] = Bs[kk][tx + j * 16];
      #pragma unroll
      for (int i = 0; i < 8; ++i)
        #pragma unroll
        for (int j = 0; j < 8; ++j)
          acc[i][j] = fmaf(a[i], b[j], acc[i][j]);
    }
    __syncthreads();
  }
  #pragma unroll
  for (int i = 0; i < 8; ++i) {
    size_t rg = bm * 128 + ty + i * 16;
    #pragma unroll
    for (int j = 0; j < 8; ++j) {
      int n = bn * 128 + tx + j * 16;
      out[rg * 1024 + n] = acc[i][j];
    }
  }
}

template<int M, int C>
__device__ __forceinline__ void fold_round(float* A, int lane) {
  bool bit = (lane & M) != 0;
  #pragma unroll
  for (int j = 0; j < C; ++j) {
    float x = A[j], y = A[j + C];
    float snd = bit ? x : y;   // value the partner needs
    float kp  = bit ? y : x;   // value I keep
    A[j] = kp + __shfl_xor(snd, M, 64);
  }
}

// Persistent sequential scan: 256 WGs x 512 threads. WG owns 8 state columns (sp = wg*8+cc).
// Af slice in LDS pitch-9 (conflict-free b32). Each lane owns distinct s values; 64 accs (8sp x 8b).
// Cross-XCD h exchange via relaxed SYSTEM-scope atomics (sc0 sc1, IF$-coherent, no cache fences).
__global__ __launch_bounds__(512) void scan_kernel(const float* __restrict__ AfT, const float* __restrict__ dlt,
                                                   const float* __restrict__ Bx, float* __restrict__ hs,
                                                   float* __restrict__ hbuf, int* __restrict__ flags,
                                                   float* __restrict__ hlast) {
  __shared__ float smem[2048 * 9 + 512];  // Af pitch-9 (73.7KB) + red [8][64]
  float* red = smem + 2048 * 9;
  const int wg = blockIdx.x;
  const int tid = threadIdx.x;
  const int lane = tid & 63;
  const int w = tid >> 6;                  // wave 0..7
  const int s_l = w * 256 + lane;          // this thread's base s (i adds 64)

  // stage Af slice: AfT[wg][s][c] -> smem[s*9 + c]
  #pragma unroll
  for (int q = 0; q < 32; ++q) {
    int idx = q * 512 + tid;
    smem[(idx >> 3) * 9 + (idx & 7)] = AfT[(size_t)wg * 16384 + idx];
  }
  __syncthreads();

  // update-lane constants (tid < 64): bb = batch, cc = sp offset
  const int bb = tid >> 3;
  const int cc = tid & 7;
  const int sp = wg * 8 + cc;
  // fold-result mapping: lane holds acc a = bitrev6(lane); a = c*8 + b
  const int rsp = ((lane & 1) << 2) | (lane & 2) | ((lane >> 2) & 1);
  const int xb  = (lane >> 3) & 7;
  const int rb  = ((xb & 1) << 2) | (xb & 2) | ((xb >> 2) & 1);

  float hreg = 0.f;
  if (tid < 64) hreg = hbuf[(size_t)bb * 2048 + sp];  // h_old register-carried

  #pragma unroll 1
  for (int t = 0; t < T_STEPS; ++t) {
    float dv = 0.f, bxv = 0.f;
    if (tid < 64) {
      size_t row = (size_t)t * 8 + bb;
      dv  = dlt[row * 2048 + sp];
      bxv = Bx[row * 2048 + sp];
    }
    const float* hcur = hbuf + (size_t)(t & 1) * 16384;  // [b][s]
    float h[32];
    #pragma unroll
    for (int i = 0; i < 4; ++i)
      #pragma unroll
      for (int b = 0; b < 8; ++b)
        h[i * 8 + b] = __hip_atomic_load(hcur + (size_t)b * 2048 + s_l + i * 64,
                                         __ATOMIC_RELAXED, __HIP_MEMORY_SCOPE_SYSTEM);
    float A[64];
    #pragma unroll
    for (int a = 0; a < 64; ++a) A[a] = 0.f;
    #pragma unroll
    for (int i = 0; i < 4; ++i) {
      int s = s_l + i * 64;
      const float* afr = &smem[s * 9];
      #pragma unroll
      for (int c = 0; c < 8; ++c) {
        float af = afr[c];
        #pragma unroll
        for (int b = 0; b < 8; ++b)
          A[c * 8 + b] = fmaf(af, h[i * 8 + b], A[c * 8 + b]);
      }
    }
    // fold-butterfly: 63 shfl; lane ends with total for acc bitrev6(lane)
    fold_round<1, 32>(A, lane);
    fold_round<2, 16>(A, lane);
    fold_round<4, 8>(A, lane);
    fold_round<8, 4>(A, lane);
    fold_round<16, 2>(A, lane);
    fold_round<32, 1>(A, lane);
    red[w * 64 + rb * 8 + rsp] = A[0];
    __syncthreads();
    if (tid < 64) {
      float outv = red[tid] + red[64 + tid] + red[128 + tid] + red[192 + tid]
                 + red[256 + tid] + red[320 + tid] + red[384 + tid] + red[448 + tid];
      float hn = fmaf(dv, outv + bxv - hreg, hreg);
      hreg = hn;
      hs[((size_t)t * 8 + bb) * 2048 + sp] = hn;           // normal store (read by gemm_y later)
      __hip_atomic_store(hbuf + (size_t)((t + 1) & 1) * 16384 + (size_t)bb * 2048 + sp, hn,
                         __ATOMIC_RELAXED, __HIP_MEMORY_SCOPE_SYSTEM);
      if (t == T_STEPS - 1) hlast[(size_t)bb * 2048 + sp] = hn;
    }
    if (tid == 0) {
      asm volatile("s_waitcnt vmcnt(0)" ::: "memory");  // h stores acked at coherence point
      __hip_atomic_store(&flags[wg], t + 1, __ATOMIC_RELAXED, __HIP_MEMORY_SCOPE_SYSTEM);
    }
    if (w == 0) {
      for (;;) {
        int f0 = __hip_atomic_load(&flags[lane],       __ATOMIC_RELAXED, __HIP_MEMORY_SCOPE_SYSTEM);
        int f1 = __hip_atomic_load(&flags[lane + 64],  __ATOMIC_RELAXED, __HIP_MEMORY_SCOPE_SYSTEM);
        int f2 = __hip_atomic_load(&flags[lane + 128], __ATOMIC_RELAXED, __HIP_MEMORY_SCOPE_SYSTEM);
        int f3 = __hip_atomic_load(&flags[lane + 192], __ATOMIC_RELAXED, __HIP_MEMORY_SCOPE_SYSTEM);
        int ok = (f0 > t) && (f1 > t) && (f2 > t) && (f3 > t);
        if (__all(ok)) break;
        __builtin_amdgcn_s_sleep(4);
      }
    }
    __syncthreads();
  }
}

extern "C" void kernel_launch(void* const* d_in, const int* in_sizes, int n_in,
                              void* d_out, int out_size, void* d_ws, size_t ws_size,
                              hipStream_t stream) {
  const float* x      = (const float*)d_in[0];
  const float* h_prev = (const float*)d_in[1];
  const float* WA     = (const float*)d_in[2];
  const float* WB     = (const float*)d_in[3];
  const float* WC     = (const float*)d_in[4];
  const float* Wd     = (const float*)d_in[5];
  const float* bias   = (const float*)d_in[6];
  float* out = (float*)d_out;
  float* w = (float*)d_ws;
  float* AfT  = w + OFF_AFT;
  float* Gcat = w + OFF_GCAT;
  float* CfT  = w + OFF_CFT;
  float* dlt  = w + OFF_DELTA;
  float* Bx   = w + OFF_BX;
  float* hs   = w + OFF_HS;
  float* hbuf = w + OFF_HBUF;
  int*   flags = (int*)(w + OFF_FLAGS);

  fold_A <<<4096, 256, 0, stream>>>(WA, AfT);
  fold_GC<<<4096, 256, 0, stream>>>(Wd, WB, Gcat);
  fold_C <<<2048, 256, 0, stream>>>(WC, CfT);
  init_h <<<64,   256, 0, stream>>>(h_prev, hbuf, flags);
  gemm_dbx<<<dim3(32, 64), 256, 0, stream>>>(x, Gcat, bias, dlt, Bx);
  scan_kernel<<<256, 512, 0, stream>>>(AfT, dlt, Bx, hs, hbuf, flags, out + 8388608);
  gemm_y<<<dim3(8, 64), 256, 0, stream>>>(hs, CfT, out);
}

// Round 3
// 7000.922 us; speedup vs baseline: 2.9633x; 1.2854x over previous
//
#include <hip/hip_runtime.h>
#include <hip/hip_bf16.h>

#define T_STEPS 1024
// ws layout (float offsets)
#define OFF_AFT   0ull
#define OFF_GCAT  4194304ull
#define OFF_CFT   8388608ull
#define OFF_DELTA 10485760ull
#define OFF_BX    27262976ull
#define OFF_HS    44040192ull
#define OFF_HBUF  60817408ull   // unsigned[2][16384] tagged bf16 h

__device__ __forceinline__ void build_oct_tables(int tid, int (*Is)[8], float (*Sg)[8]) {
  if (tid < 64) {
    int i = tid >> 3, j = tid & 7;
    int k = 0; float s = 0.f;
    if (i == 0)      { k = j; s = 1.f; }
    else if (j == 0) { k = i; s = 1.f; }
    else if (i == j) { k = 0; s = -1.f; }
    else {
      const int T7[7][3] = {{1,2,4},{2,3,5},{3,4,6},{4,5,7},{5,6,1},{6,7,2},{7,1,3}};
      for (int t = 0; t < 7; ++t) {
        int a = T7[t][0], b = T7[t][1], c = T7[t][2];
        const int P[3][3] = {{a,b,c},{b,c,a},{c,a,b}};
        for (int r = 0; r < 3; ++r) {
          if (i == P[r][0] && j == P[r][1]) { k = P[r][2]; s = 1.f; }
          if (i == P[r][1] && j == P[r][0]) { k = P[r][2]; s = -1.f; }
        }
      }
    }
    Is[j][k] = i; Sg[j][k] = s;
  }
  __syncthreads();
}

// AfT_blocked[blk=sp>>3][s][c=sp&7] = Af[sp][s],  Af[k*256+o][j*256+n] = Sg[j][k]*WA[i][o][n]
__global__ __launch_bounds__(256) void fold_A(const float* __restrict__ WA, float* __restrict__ AfT) {
  __shared__ int Is[8][8]; __shared__ float Sg[8][8];
  build_oct_tables(threadIdx.x, Is, Sg);
  int g4 = blockIdx.x * 256 + threadIdx.x;   // 0..1048575
  int c4  = (g4 & 1) * 4;
  int s   = (g4 >> 1) & 2047;
  int blk = g4 >> 12;
  int j = s >> 8, n = s & 255;
  int spbase = blk * 8 + c4;
  int k = spbase >> 8;
  int i = Is[j][k]; float sg = Sg[j][k];
  const float* wa = WA + (size_t)i * 65536 + n;
  float4 v;
  v.x = sg * wa[(size_t)((spbase + 0) & 255) * 256];
  v.y = sg * wa[(size_t)((spbase + 1) & 255) * 256];
  v.z = sg * wa[(size_t)((spbase + 2) & 255) * 256];
  v.w = sg * wa[(size_t)((spbase + 3) & 255) * 256];
  *(float4*)(AfT + (size_t)g4 * 4) = v;
}

// Gcat[d][0..2047] = Wdelta[s][d],  Gcat[d][2048+sp] = Bf[sp][d] = Sg[j][k]*WB[i][o][n]
__global__ __launch_bounds__(256) void fold_GC(const float* __restrict__ Wd, const float* __restrict__ WB,
                                               float* __restrict__ Gcat) {
  __shared__ int Is[8][8]; __shared__ float Sg[8][8];
  build_oct_tables(threadIdx.x, Is, Sg);
  int g4 = blockIdx.x * 256 + threadIdx.x;   // 0..1048575 (1024 rows x 1024 float4)
  int col = (g4 & 1023) * 4;
  int d = g4 >> 10;
  float4 v;
  if (col < 2048) {
    v.x = Wd[(size_t)(col + 0) * 1024 + d];
    v.y = Wd[(size_t)(col + 1) * 1024 + d];
    v.z = Wd[(size_t)(col + 2) * 1024 + d];
    v.w = Wd[(size_t)(col + 3) * 1024 + d];
  } else {
    int sp = col - 2048;
    int k = sp >> 8;
    int j = d >> 7, n = d & 127;
    int i = Is[j][k]; float sg = Sg[j][k];
    const float* wb = WB + (size_t)i * 32768 + n;
    v.x = sg * wb[(size_t)((sp + 0) & 255) * 128];
    v.y = sg * wb[(size_t)((sp + 1) & 255) * 128];
    v.z = sg * wb[(size_t)((sp + 2) & 255) * 128];
    v.w = sg * wb[(size_t)((sp + 3) & 255) * 128];
  }
  *(float4*)(Gcat + (size_t)g4 * 4) = v;
}

// CfT[s][d] = Cf[d][s] = Sg[j][k]*WC[i][o][n]  (d=k*128+o, s=j*256+n)
__global__ __launch_bounds__(256) void fold_C(const float* __restrict__ WC, float* __restrict__ CfT) {
  __shared__ int Is[8][8]; __shared__ float Sg[8][8];
  build_oct_tables(threadIdx.x, Is, Sg);
  int g4 = blockIdx.x * 256 + threadIdx.x;   // 0..524287 (2048 rows x 256 float4)
  int d0 = (g4 & 255) * 4;
  int s  = g4 >> 8;
  int j = s >> 8, n = s & 255;
  int k = d0 >> 7;
  int i = Is[j][k]; float sg = Sg[j][k];
  const float* wc = WC + (size_t)i * 32768 + n;
  float4 v;
  v.x = sg * wc[(size_t)((d0 + 0) & 127) * 256];
  v.y = sg * wc[(size_t)((d0 + 1) & 127) * 256];
  v.z = sg * wc[(size_t)((d0 + 2) & 127) * 256];
  v.w = sg * wc[(size_t)((d0 + 3) & 127) * 256];
  *(float4*)(CfT + (size_t)g4 * 4) = v;
}

__device__ __forceinline__ unsigned pack_bf16(float x, unsigned tag) {
  unsigned u = __float_as_uint(x);
  unsigned r = (u + 0x7FFFu + ((u >> 16) & 1u)) >> 16;  // RNE-ish bf16
  return ((tag & 0xFFFFu) << 16) | r;
}

// hq layout [2][b][s]; buf0 seeded with tag 0 = h_prev, buf1 sentinel
__global__ __launch_bounds__(256) void init_h(const float* __restrict__ h_prev, unsigned* __restrict__ hq) {
  int gid = blockIdx.x * 256 + threadIdx.x;  // 0..16383
  hq[gid]         = pack_bf16(h_prev[gid], 0u);
  hq[16384 + gid] = 0xFFFF0000u;
}

// C = X[8192x1024] * Gcat[1024x4096]; cols<2048 -> sigmoid(+bias) -> delta[t][b][s]; else Bx[t][b][s]
__global__ __launch_bounds__(256) void gemm_dbx(const float* __restrict__ X, const float* __restrict__ G,
                                                const float* __restrict__ bias,
                                                float* __restrict__ dlt, float* __restrict__ Bx) {
  __shared__ float As[16][128];
  __shared__ float Bs[16][128];
  const int bn = blockIdx.x, bm = blockIdx.y;
  const int tid = threadIdx.x;
  const int tx = tid & 15, ty = tid >> 4;
  float acc[8][8] = {};
  for (int kt = 0; kt < 1024; kt += 16) {
    #pragma unroll
    for (int q = 0; q < 2; ++q) {
      int slot = tid * 2 + q;
      int r = slot >> 2, c4 = slot & 3;
      float4 v = *(const float4*)(X + (size_t)(bm * 128 + r) * 1024 + kt + c4 * 4);
      As[c4 * 4 + 0][r] = v.x; As[c4 * 4 + 1][r] = v.y;
      As[c4 * 4 + 2][r] = v.z; As[c4 * 4 + 3][r] = v.w;
    }
    #pragma unroll
    for (int q = 0; q < 2; ++q) {
      int slot = tid * 2 + q;
      int kr = slot >> 5, c4 = slot & 31;
      *(float4*)(&Bs[kr][c4 * 4]) = *(const float4*)(G + (size_t)(kt + kr) * 4096 + bn * 128 + c4 * 4);
    }
    __syncthreads();
    #pragma unroll
    for (int kk = 0; kk < 16; ++kk) {
      float a[8], b[8];
      #pragma unroll
      for (int i = 0; i < 8; ++i) a[i] = As[kk][ty + i * 16];
      #pragma unroll
      for (int j = 0; j < 8; ++j) b[j] = Bs[kk][tx + j * 16];
      #pragma unroll
      for (int i = 0; i < 8; ++i)
        #pragma unroll
        for (int j = 0; j < 8; ++j)
          acc[i][j] = fmaf(a[i], b[j], acc[i][j]);
    }
    __syncthreads();
  }
  const bool isDelta = (bn < 16);
  #pragma unroll
  for (int i = 0; i < 8; ++i) {
    int r = bm * 128 + ty + i * 16;
    int t = r & 1023, b = r >> 10;
    size_t base = ((size_t)t * 8 + b) * 2048;
    #pragma unroll
    for (int j = 0; j < 8; ++j) {
      int n = bn * 128 + tx + j * 16;
      float v = acc[i][j];
      if (isDelta) {
        v += bias[n];
        v = 1.0f / (1.0f + expf(-v));
        dlt[base + n] = v;
      } else {
        Bx[base + (n - 2048)] = v;
      }
    }
  }
}

// y[b][t][d] = sum_s hs[t*8+b][s] * CfT[s][d]
__global__ __launch_bounds__(256) void gemm_y(const float* __restrict__ HS, const float* __restrict__ CfT,
                                              float* __restrict__ out) {
  __shared__ float As[16][128];
  __shared__ float Bs[16][128];
  const int bn = blockIdx.x, bm = blockIdx.y;
  const int tid = threadIdx.x;
  const int tx = tid & 15, ty = tid >> 4;
  float acc[8][8] = {};
  for (int kt = 0; kt < 2048; kt += 16) {
    #pragma unroll
    for (int q = 0; q < 2; ++q) {
      int slot = tid * 2 + q;
      int r = slot >> 2, c4 = slot & 3;
      int rg = bm * 128 + r;
      const float* arow = HS + (size_t)((rg & 1023) * 8 + (rg >> 10)) * 2048;
      float4 v = *(const float4*)(arow + kt + c4 * 4);
      As[c4 * 4 + 0][r] = v.x; As[c4 * 4 + 1][r] = v.y;
      As[c4 * 4 + 2][r] = v.z; As[c4 * 4 + 3][r] = v.w;
    }
    #pragma unroll
    for (int q = 0; q < 2; ++q) {
      int slot = tid * 2 + q;
      int kr = slot >> 5, c4 = slot & 31;
      *(float4*)(&Bs[kr][c4 * 4]) = *(const float4*)(CfT + (size_t)(kt + kr) * 1024 + bn * 128 + c4 * 4);
    }
    __syncthreads();
    #pragma unroll
    for (int kk = 0; kk < 16; ++kk) {
      float a[8], b[8];
      #pragma unroll
      for (int i = 0; i < 8; ++i) a[i] = As[kk][ty + i * 16];
      #pragma unroll
      for (int j = 0; j < 8; ++j) b[j] = Bs[kk][tx + j * 16];
      #pragma unroll
      for (int i = 0; i < 8; ++i)
        #pragma unroll
        for (int j = 0; j < 8; ++j)
          acc[i][j] = fmaf(a[i], b[j], acc[i][j]);
    }
    __syncthreads();
  }
  #pragma unroll
  for (int i = 0; i < 8; ++i) {
    size_t rg = bm * 128 + ty + i * 16;
    #pragma unroll
    for (int j = 0; j < 8; ++j) {
      int n = bn * 128 + tx + j * 16;
      out[rg * 1024 + n] = acc[i][j];
    }
  }
}

template<int M, int C>
__device__ __forceinline__ void fold_round(float* A, int lane) {
  bool bit = (lane & M) != 0;
  #pragma unroll
  for (int j = 0; j < C; ++j) {
    float x = A[j], y = A[j + C];
    float snd = bit ? x : y;   // value the partner needs
    float kp  = bit ? y : x;   // value I keep
    A[j] = kp + __shfl_xor(snd, M, 64);
  }
}

// Persistent sequential scan, self-timed via tagged bf16 h broadcast.
// WG owns 8 state columns (sp = wg*8+cc). Af slice in LDS pitch-9 (conflict-free).
// h element = {tag:16 | bf16:16}, double-buffered; consumers reload stale elements only.
__global__ __launch_bounds__(512) void scan_kernel(const float* __restrict__ AfT, const float* __restrict__ dlt,
                                                   const float* __restrict__ Bx, float* __restrict__ hs,
                                                   unsigned* __restrict__ hq, const float* __restrict__ h_prev,
                                                   float* __restrict__ hlast) {
  __shared__ float smem[2048 * 9 + 512];  // Af pitch-9 (73.7KB) + red [8][64]
  float* red = smem + 2048 * 9;
  const int wg = blockIdx.x;
  const int tid = threadIdx.x;
  const int lane = tid & 63;
  const int w = tid >> 6;                  // wave 0..7
  const int s_l = w * 256 + lane;          // this thread's base s (i adds 64)

  // stage Af slice: AfT[wg][s][c] -> smem[s*9 + c]
  #pragma unroll
  for (int q = 0; q < 32; ++q) {
    int idx = q * 512 + tid;
    smem[(idx >> 3) * 9 + (idx & 7)] = AfT[(size_t)wg * 16384 + idx];
  }
  __syncthreads();

  // update-lane constants (tid < 64 == wave 0): bb = batch, cc = sp offset
  const int bb = tid >> 3;
  const int cc = tid & 7;
  const int sp = wg * 8 + cc;
  // fold-result mapping: lane holds acc a = bitrev6(lane); a = c*8 + b
  const int rsp = ((lane & 1) << 2) | (lane & 2) | ((lane >> 2) & 1);
  const int xb  = (lane >> 3) & 7;
  const int rb  = ((xb & 1) << 2) | (xb & 2) | ((xb >> 2) & 1);

  float hreg = 0.f;
  if (tid < 64) hreg = h_prev[(size_t)bb * 2048 + sp];  // fp32 h carried in register

  #pragma unroll 1
  for (int t = 0; t < T_STEPS; ++t) {
    float dv = 0.f, bxv = 0.f;
    if (tid < 64) {
      size_t row = (size_t)t * 8 + bb;
      dv  = dlt[row * 2048 + sp];
      bxv = Bx[row * 2048 + sp];
    }
    const unsigned want = (unsigned)t & 0xFFFFu;
    const unsigned* bq = hq + (size_t)(t & 1) * 16384;
    unsigned hv[32];
    #pragma unroll
    for (int j = 0; j < 32; ++j)
      hv[j] = __hip_atomic_load(bq + (size_t)(j & 7) * 2048 + s_l + (j >> 3) * 64,
                                __ATOMIC_RELAXED, __HIP_MEMORY_SCOPE_SYSTEM);
    for (;;) {
      bool stale = false;
      #pragma unroll
      for (int j = 0; j < 32; ++j) stale |= ((hv[j] >> 16) != want);
      if (!__any(stale)) break;
      __builtin_amdgcn_s_sleep(1);
      #pragma unroll
      for (int j = 0; j < 32; ++j)
        if ((hv[j] >> 16) != want)
          hv[j] = __hip_atomic_load(bq + (size_t)(j & 7) * 2048 + s_l + (j >> 3) * 64,
                                    __ATOMIC_RELAXED, __HIP_MEMORY_SCOPE_SYSTEM);
    }
    float h[32];
    #pragma unroll
    for (int j = 0; j < 32; ++j) h[j] = __uint_as_float(hv[j] << 16);

    float A[64];
    #pragma unroll
    for (int a = 0; a < 64; ++a) A[a] = 0.f;
    #pragma unroll
    for (int i = 0; i < 4; ++i) {
      int s = s_l + i * 64;
      const float* afr = &smem[s * 9];
      #pragma unroll
      for (int c = 0; c < 8; ++c) {
        float af = afr[c];
        #pragma unroll
        for (int b = 0; b < 8; ++b)
          A[c * 8 + b] = fmaf(af, h[i * 8 + b], A[c * 8 + b]);
      }
    }
    // fold-butterfly: 63 shfl; lane ends with total for acc bitrev6(lane)
    fold_round<1, 32>(A, lane);
    fold_round<2, 16>(A, lane);
    fold_round<4, 8>(A, lane);
    fold_round<8, 4>(A, lane);
    fold_round<16, 2>(A, lane);
    fold_round<32, 1>(A, lane);
    red[w * 64 + rb * 8 + rsp] = A[0];
    __syncthreads();
    if (tid < 64) {
      float outv = red[tid] + red[64 + tid] + red[128 + tid] + red[192 + tid]
                 + red[256 + tid] + red[320 + tid] + red[384 + tid] + red[448 + tid];
      float hn = fmaf(dv, outv + bxv - hreg, hreg);
      hreg = hn;
      hs[((size_t)t * 8 + bb) * 2048 + sp] = hn;           // fp32 history for gemm_y
      __hip_atomic_store(hq + (size_t)((t + 1) & 1) * 16384 + (size_t)bb * 2048 + sp,
                         pack_bf16(hn, (unsigned)(t + 1)),
                         __ATOMIC_RELAXED, __HIP_MEMORY_SCOPE_SYSTEM);
      if (t == T_STEPS - 1) hlast[(size_t)bb * 2048 + sp] = hn;
    }
    __syncthreads();   // protect red for next step's writes
  }
}

extern "C" void kernel_launch(void* const* d_in, const int* in_sizes, int n_in,
                              void* d_out, int out_size, void* d_ws, size_t ws_size,
                              hipStream_t stream) {
  const float* x      = (const float*)d_in[0];
  const float* h_prev = (const float*)d_in[1];
  const float* WA     = (const float*)d_in[2];
  const float* WB     = (const float*)d_in[3];
  const float* WC     = (const float*)d_in[4];
  const float* Wd     = (const float*)d_in[5];
  const float* bias   = (const float*)d_in[6];
  float* out = (float*)d_out;
  float* w = (float*)d_ws;
  float* AfT  = w + OFF_AFT;
  float* Gcat = w + OFF_GCAT;
  float* CfT  = w + OFF_CFT;
  float* dlt  = w + OFF_DELTA;
  float* Bx   = w + OFF_BX;
  float* hs   = w + OFF_HS;
  unsigned* hq = (unsigned*)(w + OFF_HBUF);

  fold_A <<<4096, 256, 0, stream>>>(WA, AfT);
  fold_GC<<<4096, 256, 0, stream>>>(Wd, WB, Gcat);
  fold_C <<<2048, 256, 0, stream>>>(WC, CfT);
  init_h <<<64,   256, 0, stream>>>(h_prev, hq);
  gemm_dbx<<<dim3(32, 64), 256, 0, stream>>>(x, Gcat, bias, dlt, Bx);
  scan_kernel<<<256, 512, 0, stream>>>(AfT, dlt, Bx, hs, hq, h_prev, out + 8388608);
  gemm_y<<<dim3(8, 64), 256, 0, stream>>>(hs, CfT, out);
}

// Round 4
// 6417.402 us; speedup vs baseline: 3.2327x; 1.0909x over previous
//
#include <hip/hip_runtime.h>
#include <hip/hip_bf16.h>

#define T_STEPS 1024
// ws layout (float offsets)
#define OFF_AFT   0ull          // AfM row-major [2048][2048] fp32
#define OFF_GCAT  4194304ull
#define OFF_CFT   8388608ull
#define OFF_DELTA 10485760ull
#define OFF_BX    27262976ull
#define OFF_HS    44040192ull
#define OFF_HBUF  60817408ull   // ushort[2][16384] bf16 h chunks + int tagm[128]

typedef short short8 __attribute__((ext_vector_type(8)));
typedef float f32x4 __attribute__((ext_vector_type(4)));

__device__ __forceinline__ void build_oct_tables(int tid, int (*Is)[8], float (*Sg)[8]) {
  if (tid < 64) {
    int i = tid >> 3, j = tid & 7;
    int k = 0; float s = 0.f;
    if (i == 0)      { k = j; s = 1.f; }
    else if (j == 0) { k = i; s = 1.f; }
    else if (i == j) { k = 0; s = -1.f; }
    else {
      const int T7[7][3] = {{1,2,4},{2,3,5},{3,4,6},{4,5,7},{5,6,1},{6,7,2},{7,1,3}};
      for (int t = 0; t < 7; ++t) {
        int a = T7[t][0], b = T7[t][1], c = T7[t][2];
        const int P[3][3] = {{a,b,c},{b,c,a},{c,a,b}};
        for (int r = 0; r < 3; ++r) {
          if (i == P[r][0] && j == P[r][1]) { k = P[r][2]; s = 1.f; }
          if (i == P[r][1] && j == P[r][0]) { k = P[r][2]; s = -1.f; }
        }
      }
    }
    Is[j][k] = i; Sg[j][k] = s;
  }
  __syncthreads();
}

__device__ __forceinline__ unsigned short bf16r(float x) {
  unsigned u = __float_as_uint(x);
  return (unsigned short)((u + 0x7FFFu + ((u >> 16) & 1u)) >> 16);
}

// AfM[sp][s] row-major: Af[k8*256+o][j8*256+n] = Sg[j8][k8]*WA[Is[j8][k8]][o][n]
__global__ __launch_bounds__(256) void fold_A(const float* __restrict__ WA, float* __restrict__ AfM) {
  __shared__ int Is[8][8]; __shared__ float Sg[8][8];
  build_oct_tables(threadIdx.x, Is, Sg);
  int g4 = blockIdx.x * 256 + threadIdx.x;   // 0..1048575 (2048 sp x 512 float4)
  int sp = g4 >> 9;
  int s4 = (g4 & 511) * 4;
  int k8 = sp >> 8, o = sp & 255;
  int j8 = s4 >> 8, n = s4 & 255;
  int i = Is[j8][k8]; float sg = Sg[j8][k8];
  float4 v = *(const float4*)(WA + (size_t)i * 65536 + (size_t)o * 256 + n);
  v.x *= sg; v.y *= sg; v.z *= sg; v.w *= sg;
  *(float4*)(AfM + (size_t)g4 * 4) = v;
}

// Gcat[d][0..2047] = Wdelta[s][d],  Gcat[d][2048+sp] = Bf[sp][d]
__global__ __launch_bounds__(256) void fold_GC(const float* __restrict__ Wd, const float* __restrict__ WB,
                                               float* __restrict__ Gcat) {
  __shared__ int Is[8][8]; __shared__ float Sg[8][8];
  build_oct_tables(threadIdx.x, Is, Sg);
  int g4 = blockIdx.x * 256 + threadIdx.x;
  int col = (g4 & 1023) * 4;
  int d = g4 >> 10;
  float4 v;
  if (col < 2048) {
    v.x = Wd[(size_t)(col + 0) * 1024 + d];
    v.y = Wd[(size_t)(col + 1) * 1024 + d];
    v.z = Wd[(size_t)(col + 2) * 1024 + d];
    v.w = Wd[(size_t)(col + 3) * 1024 + d];
  } else {
    int sp = col - 2048;
    int k = sp >> 8;
    int j = d >> 7, n = d & 127;
    int i = Is[j][k]; float sg = Sg[j][k];
    const float* wb = WB + (size_t)i * 32768 + n;
    v.x = sg * wb[(size_t)((sp + 0) & 255) * 128];
    v.y = sg * wb[(size_t)((sp + 1) & 255) * 128];
    v.z = sg * wb[(size_t)((sp + 2) & 255) * 128];
    v.w = sg * wb[(size_t)((sp + 3) & 255) * 128];
  }
  *(float4*)(Gcat + (size_t)g4 * 4) = v;
}

// CfT[s][d] = Cf[d][s]
__global__ __launch_bounds__(256) void fold_C(const float* __restrict__ WC, float* __restrict__ CfT) {
  __shared__ int Is[8][8]; __shared__ float Sg[8][8];
  build_oct_tables(threadIdx.x, Is, Sg);
  int g4 = blockIdx.x * 256 + threadIdx.x;
  int d0 = (g4 & 255) * 4;
  int s  = g4 >> 8;
  int j = s >> 8, n = s & 255;
  int k = d0 >> 7;
  int i = Is[j][k]; float sg = Sg[j][k];
  const float* wc = WC + (size_t)i * 32768 + n;
  float4 v;
  v.x = sg * wc[(size_t)((d0 + 0) & 127) * 256];
  v.y = sg * wc[(size_t)((d0 + 1) & 127) * 256];
  v.z = sg * wc[(size_t)((d0 + 2) & 127) * 256];
  v.w = sg * wc[(size_t)((d0 + 3) & 127) * 256];
  *(float4*)(CfT + (size_t)g4 * 4) = v;
}

// hx buf0: chunk p (s=p*16..p*16+15): hx[p*128 + b*16 + sp] = bf16(h_prev[b*2048 + p*16+sp]); tagm=0
__global__ __launch_bounds__(256) void init_h(const float* __restrict__ h_prev, unsigned short* __restrict__ hx,
                                              int* __restrict__ tagm) {
  int gid = blockIdx.x * 256 + threadIdx.x;  // 0..16383 = b*2048 + s
  int b = gid >> 11, s = gid & 2047;
  hx[(s >> 4) * 128 + b * 16 + (s & 15)] = bf16r(h_prev[gid]);
  if (blockIdx.x == 0 && threadIdx.x < 128) tagm[threadIdx.x] = 0;
}

// C = X[8192x1024] * Gcat[1024x4096]; cols<2048 -> sigmoid(+bias) -> delta[t][b][s]; else Bx[t][b][s]
__global__ __launch_bounds__(256) void gemm_dbx(const float* __restrict__ X, const float* __restrict__ G,
                                                const float* __restrict__ bias,
                                                float* __restrict__ dlt, float* __restrict__ Bx) {
  __shared__ float As[16][128];
  __shared__ float Bs[16][128];
  const int bn = blockIdx.x, bm = blockIdx.y;
  const int tid = threadIdx.x;
  const int tx = tid & 15, ty = tid >> 4;
  float acc[8][8] = {};
  for (int kt = 0; kt < 1024; kt += 16) {
    #pragma unroll
    for (int q = 0; q < 2; ++q) {
      int slot = tid * 2 + q;
      int r = slot >> 2, c4 = slot & 3;
      float4 v = *(const float4*)(X + (size_t)(bm * 128 + r) * 1024 + kt + c4 * 4);
      As[c4 * 4 + 0][r] = v.x; As[c4 * 4 + 1][r] = v.y;
      As[c4 * 4 + 2][r] = v.z; As[c4 * 4 + 3][r] = v.w;
    }
    #pragma unroll
    for (int q = 0; q < 2; ++q) {
      int slot = tid * 2 + q;
      int kr = slot >> 5, c4 = slot & 31;
      *(float4*)(&Bs[kr][c4 * 4]) = *(const float4*)(G + (size_t)(kt + kr) * 4096 + bn * 128 + c4 * 4);
    }
    __syncthreads();
    #pragma unroll
    for (int kk = 0; kk < 16; ++kk) {
      float a[8], b[8];
      #pragma unroll
      for (int i = 0; i < 8; ++i) a[i] = As[kk][ty + i * 16];
      #pragma unroll
      for (int j = 0; j < 8; ++j) b[j] = Bs[kk][tx + j * 16];
      #pragma unroll
      for (int i = 0; i < 8; ++i)
        #pragma unroll
        for (int j = 0; j < 8; ++j)
          acc[i][j] = fmaf(a[i], b[j], acc[i][j]);
    }
    __syncthreads();
  }
  const bool isDelta = (bn < 16);
  #pragma unroll
  for (int i = 0; i < 8; ++i) {
    int r = bm * 128 + ty + i * 16;
    int t = r & 1023, b = r >> 10;
    size_t base = ((size_t)t * 8 + b) * 2048;
    #pragma unroll
    for (int j = 0; j < 8; ++j) {
      int n = bn * 128 + tx + j * 16;
      float v = acc[i][j];
      if (isDelta) {
        v += bias[n];
        v = 1.0f / (1.0f + expf(-v));
        dlt[base + n] = v;
      } else {
        Bx[base + (n - 2048)] = v;
      }
    }
  }
}

// y[b][t][d] = sum_s hs[t*8+b][s] * CfT[s][d]
__global__ __launch_bounds__(256) void gemm_y(const float* __restrict__ HS, const float* __restrict__ CfT,
                                              float* __restrict__ out) {
  __shared__ float As[16][128];
  __shared__ float Bs[16][128];
  const int bn = blockIdx.x, bm = blockIdx.y;
  const int tid = threadIdx.x;
  const int tx = tid & 15, ty = tid >> 4;
  float acc[8][8] = {};
  for (int kt = 0; kt < 2048; kt += 16) {
    #pragma unroll
    for (int q = 0; q < 2; ++q) {
      int slot = tid * 2 + q;
      int r = slot >> 2, c4 = slot & 3;
      int rg = bm * 128 + r;
      const float* arow = HS + (size_t)((rg & 1023) * 8 + (rg >> 10)) * 2048;
      float4 v = *(const float4*)(arow + kt + c4 * 4);
      As[c4 * 4 + 0][r] = v.x; As[c4 * 4 + 1][r] = v.y;
      As[c4 * 4 + 2][r] = v.z; As[c4 * 4 + 3][r] = v.w;
    }
    #pragma unroll
    for (int q = 0; q < 2; ++q) {
      int slot = tid * 2 + q;
      int kr = slot >> 5, c4 = slot & 31;
      *(float4*)(&Bs[kr][c4 * 4]) = *(const float4*)(CfT + (size_t)(kt + kr) * 1024 + bn * 128 + c4 * 4);
    }
    __syncthreads();
    #pragma unroll
    for (int kk = 0; kk < 16; ++kk) {
      float a[8], b[8];
      #pragma unroll
      for (int i = 0; i < 8; ++i) a[i] = As[kk][ty + i * 16];
      #pragma unroll
      for (int j = 0; j < 8; ++j) b[j] = Bs[kk][tx + j * 16];
      #pragma unroll
      for (int i = 0; i < 8; ++i)
        #pragma unroll
        for (int j = 0; j < 8; ++j)
          acc[i][j] = fmaf(a[i], b[j], acc[i][j]);
    }
    __syncthreads();
  }
  #pragma unroll
  for (int i = 0; i < 8; ++i) {
    size_t rg = bm * 128 + ty + i * 16;
    #pragma unroll
    for (int j = 0; j < 8; ++j) {
      int n = bn * 128 + tx + j * 16;
      out[rg * 1024 + n] = acc[i][j];
    }
  }
}

// Persistent scan: 128 WGs x 512 threads, WG owns 16 sp rows. A-frags in registers (bf16).
// Per step/wave: poll 128 monotone tags, 16 system u64 loads -> 8 mfma_16x16x32_bf16,
// LDS reduce, wave0 updates h and publishes bf16 chunk + tag.
__global__ __launch_bounds__(512) void scan_kernel(const float* __restrict__ AfM, const float* __restrict__ dlt,
                                                   const float* __restrict__ Bx, float* __restrict__ hs,
                                                   unsigned short* __restrict__ hx, int* __restrict__ tagm,
                                                   const float* __restrict__ h_prev, float* __restrict__ hlast) {
  __shared__ float red[8 * 128];           // [wave][sp16][b8]
  const int wg = blockIdx.x;               // 0..127
  const int tid = threadIdx.x;
  const int lane = tid & 63;
  const int w = tid >> 6;                  // wave 0..7 (K-slice of 256)
  const int row = lane & 15;               // A row (sp_local) / B col (n)
  const int g4 = (lane >> 4) & 3;          // k-group
  const int b_eff = lane & 7;              // duplicate for n>=8 (unused D cols)

  // A-frags: afr[q] = Af[wg*16+row][w*256 + q*32 + g4*8 .. +7] in bf16
  short8 afr[8];
  {
    const float* base = AfM + (size_t)(wg * 16 + row) * 2048 + w * 256 + g4 * 8;
    #pragma unroll
    for (int q = 0; q < 8; ++q) {
      float4 f0 = *(const float4*)(base + q * 32);
      float4 f1 = *(const float4*)(base + q * 32 + 4);
      short8 v;
      v[0] = (short)bf16r(f0.x); v[1] = (short)bf16r(f0.y);
      v[2] = (short)bf16r(f0.z); v[3] = (short)bf16r(f0.w);
      v[4] = (short)bf16r(f1.x); v[5] = (short)bf16r(f1.y);
      v[6] = (short)bf16r(f1.z); v[7] = (short)bf16r(f1.w);
      afr[q] = v;
    }
  }
  // B-chunk element offset (bf16 units), +q*256 per slice
  const int s0 = w * 256 + g4 * 8;
  const int elem0 = (s0 >> 4) * 128 + b_eff * 16 + (s0 & 8);

  // update-lane state (wave 0, 2 elems each): b = tid>>3, sp2 = (tid&7)*2
  const int ub = tid >> 3, usp = (tid & 7) * 2;
  float hr0 = 0.f, hr1 = 0.f;
  if (tid < 64) {
    hr0 = h_prev[(size_t)ub * 2048 + wg * 16 + usp];
    hr1 = h_prev[(size_t)ub * 2048 + wg * 16 + usp + 1];
  }

  #pragma unroll 1
  for (int t = 0; t < T_STEPS; ++t) {
    float2 dv = make_float2(0.f, 0.f), bxv = make_float2(0.f, 0.f);
    if (tid < 64) {
      size_t off = ((size_t)t * 8 + ub) * 2048 + wg * 16 + usp;
      dv  = *(const float2*)(dlt + off);
      bxv = *(const float2*)(Bx + off);
    }
    // poll monotone tags (all waves): need all 128 producers at >= t
    for (;;) {
      int f0 = __hip_atomic_load(&tagm[lane],      __ATOMIC_RELAXED, __HIP_MEMORY_SCOPE_SYSTEM);
      int f1 = __hip_atomic_load(&tagm[lane + 64], __ATOMIC_RELAXED, __HIP_MEMORY_SCOPE_SYSTEM);
      if (__all((f0 >= t) && (f1 >= t))) break;
      __builtin_amdgcn_s_sleep(1);
    }
    const unsigned short* bq = hx + (size_t)(t & 1) * 16384;
    f32x4 acc = {0.f, 0.f, 0.f, 0.f};
    #pragma unroll
    for (int q = 0; q < 8; ++q) {
      const unsigned long long* p = (const unsigned long long*)(bq + elem0 + q * 256);
      unsigned long long lo = __hip_atomic_load(p,     __ATOMIC_RELAXED, __HIP_MEMORY_SCOPE_SYSTEM);
      unsigned long long hi = __hip_atomic_load(p + 1, __ATOMIC_RELAXED, __HIP_MEMORY_SCOPE_SYSTEM);
      union { unsigned long long u[2]; short8 v; } bb;
      bb.u[0] = lo; bb.u[1] = hi;
      acc = __builtin_amdgcn_mfma_f32_16x16x32_bf16(afr[q], bb.v, acc, 0, 0, 0);
    }
    // partial D -> LDS (valid cols b<8 only); D row=(g4*4+r), col=row(lane&15)
    if (row < 8) {
      #pragma unroll
      for (int r = 0; r < 4; ++r)
        red[w * 128 + (g4 * 4 + r) * 8 + row] = acc[r];
    }
    __syncthreads();
    if (tid < 64) {
      float o0 = 0.f, o1 = 0.f;
      #pragma unroll
      for (int ww = 0; ww < 8; ++ww) {
        o0 += red[ww * 128 + usp * 8 + ub];
        o1 += red[ww * 128 + (usp + 1) * 8 + ub];
      }
      float h0 = fmaf(dv.x, o0 + bxv.x - hr0, hr0);
      float h1 = fmaf(dv.y, o1 + bxv.y - hr1, hr1);
      hr0 = h0; hr1 = h1;
      size_t off = ((size_t)t * 8 + ub) * 2048 + wg * 16 + usp;
      *(float2*)(hs + off) = make_float2(h0, h1);
      unsigned pk = (unsigned)bf16r(h0) | ((unsigned)bf16r(h1) << 16);
      __hip_atomic_store((unsigned*)(hx + (size_t)((t + 1) & 1) * 16384 + wg * 128 + ub * 16 + usp), pk,
                         __ATOMIC_RELAXED, __HIP_MEMORY_SCOPE_SYSTEM);
      if (t == T_STEPS - 1)
        *(float2*)(hlast + (size_t)ub * 2048 + wg * 16 + usp) = make_float2(h0, h1);
    }
    if (w == 0) {
      asm volatile("s_waitcnt vmcnt(0)" ::: "memory");  // publish acked at IF$ before tag
      if (tid == 0)
        __hip_atomic_store(&tagm[wg], t + 1, __ATOMIC_RELAXED, __HIP_MEMORY_SCOPE_SYSTEM);
    }
    __syncthreads();  // local waves: own chunk published; red reusable
  }
}

extern "C" void kernel_launch(void* const* d_in, const int* in_sizes, int n_in,
                              void* d_out, int out_size, void* d_ws, size_t ws_size,
                              hipStream_t stream) {
  const float* x      = (const float*)d_in[0];
  const float* h_prev = (const float*)d_in[1];
  const float* WA     = (const float*)d_in[2];
  const float* WB     = (const float*)d_in[3];
  const float* WC     = (const float*)d_in[4];
  const float* Wd     = (const float*)d_in[5];
  const float* bias   = (const float*)d_in[6];
  float* out = (float*)d_out;
  float* w = (float*)d_ws;
  float* AfM  = w + OFF_AFT;
  float* Gcat = w + OFF_GCAT;
  float* CfT  = w + OFF_CFT;
  float* dlt  = w + OFF_DELTA;
  float* Bx   = w + OFF_BX;
  float* hs   = w + OFF_HS;
  unsigned short* hx = (unsigned short*)(w + OFF_HBUF);
  int* tagm = (int*)(w + OFF_HBUF + 16384);

  fold_A <<<4096, 256, 0, stream>>>(WA, AfM);
  fold_GC<<<4096, 256, 0, stream>>>(Wd, WB, Gcat);
  fold_C <<<2048, 256, 0, stream>>>(WC, CfT);
  init_h <<<64,   256, 0, stream>>>(h_prev, hx, tagm);
  gemm_dbx<<<dim3(32, 64), 256, 0, stream>>>(x, Gcat, bias, dlt, Bx);
  scan_kernel<<<128, 512, 0, stream>>>(AfM, dlt, Bx, hs, hx, tagm, h_prev, out + 8388608);
  gemm_y<<<dim3(8, 64), 256, 0, stream>>>(hs, CfT, out);
}

// Round 5
// 5371.217 us; speedup vs baseline: 3.8624x; 1.1948x over previous
//
#include <hip/hip_runtime.h>
#include <hip/hip_bf16.h>

#define T_STEPS 1024
// ws layout (float offsets)
#define OFF_AFT   0ull          // AfM row-major [2048][2048] fp32
#define OFF_GCAT  4194304ull
#define OFF_CFT   8388608ull
#define OFF_DELTA 10485760ull
#define OFF_BX    27262976ull
#define OFF_HS    44040192ull
#define OFF_HBUF  60817408ull   // u64[2][8192] self-tagged bf16 h words

typedef short short8 __attribute__((ext_vector_type(8)));
typedef float f32x4 __attribute__((ext_vector_type(4)));

__device__ __forceinline__ void build_oct_tables(int tid, int (*Is)[8], float (*Sg)[8]) {
  if (tid < 64) {
    int i = tid >> 3, j = tid & 7;
    int k = 0; float s = 0.f;
    if (i == 0)      { k = j; s = 1.f; }
    else if (j == 0) { k = i; s = 1.f; }
    else if (i == j) { k = 0; s = -1.f; }
    else {
      const int T7[7][3] = {{1,2,4},{2,3,5},{3,4,6},{4,5,7},{5,6,1},{6,7,2},{7,1,3}};
      for (int t = 0; t < 7; ++t) {
        int a = T7[t][0], b = T7[t][1], c = T7[t][2];
        const int P[3][3] = {{a,b,c},{b,c,a},{c,a,b}};
        for (int r = 0; r < 3; ++r) {
          if (i == P[r][0] && j == P[r][1]) { k = P[r][2]; s = 1.f; }
          if (i == P[r][1] && j == P[r][0]) { k = P[r][2]; s = -1.f; }
        }
      }
    }
    Is[j][k] = i; Sg[j][k] = s;
  }
  __syncthreads();
}

__device__ __forceinline__ unsigned short bf16r(float x) {
  unsigned u = __float_as_uint(x);
  return (unsigned short)((u + 0x7FFFu + ((u >> 16) & 1u)) >> 16);
}

// AfM[sp][s] row-major: Af[k8*256+o][j8*256+n] = Sg[j8][k8]*WA[Is[j8][k8]][o][n]
__global__ __launch_bounds__(256) void fold_A(const float* __restrict__ WA, float* __restrict__ AfM) {
  __shared__ int Is[8][8]; __shared__ float Sg[8][8];
  build_oct_tables(threadIdx.x, Is, Sg);
  int g4 = blockIdx.x * 256 + threadIdx.x;   // 0..1048575 (2048 sp x 512 float4)
  int sp = g4 >> 9;
  int s4 = (g4 & 511) * 4;
  int k8 = sp >> 8, o = sp & 255;
  int j8 = s4 >> 8, n = s4 & 255;
  int i = Is[j8][k8]; float sg = Sg[j8][k8];
  float4 v = *(const float4*)(WA + (size_t)i * 65536 + (size_t)o * 256 + n);
  v.x *= sg; v.y *= sg; v.z *= sg; v.w *= sg;
  *(float4*)(AfM + (size_t)g4 * 4) = v;
}

// Gcat[d][0..2047] = Wdelta[s][d],  Gcat[d][2048+sp] = Bf[sp][d]
__global__ __launch_bounds__(256) void fold_GC(const float* __restrict__ Wd, const float* __restrict__ WB,
                                               float* __restrict__ Gcat) {
  __shared__ int Is[8][8]; __shared__ float Sg[8][8];
  build_oct_tables(threadIdx.x, Is, Sg);
  int g4 = blockIdx.x * 256 + threadIdx.x;
  int col = (g4 & 1023) * 4;
  int d = g4 >> 10;
  float4 v;
  if (col < 2048) {
    v.x = Wd[(size_t)(col + 0) * 1024 + d];
    v.y = Wd[(size_t)(col + 1) * 1024 + d];
    v.z = Wd[(size_t)(col + 2) * 1024 + d];
    v.w = Wd[(size_t)(col + 3) * 1024 + d];
  } else {
    int sp = col - 2048;
    int k = sp >> 8;
    int j = d >> 7, n = d & 127;
    int i = Is[j][k]; float sg = Sg[j][k];
    const float* wb = WB + (size_t)i * 32768 + n;
    v.x = sg * wb[(size_t)((sp + 0) & 255) * 128];
    v.y = sg * wb[(size_t)((sp + 1) & 255) * 128];
    v.z = sg * wb[(size_t)((sp + 2) & 255) * 128];
    v.w = sg * wb[(size_t)((sp + 3) & 255) * 128];
  }
  *(float4*)(Gcat + (size_t)g4 * 4) = v;
}

// CfT[s][d] = Cf[d][s]
__global__ __launch_bounds__(256) void fold_C(const float* __restrict__ WC, float* __restrict__ CfT) {
  __shared__ int Is[8][8]; __shared__ float Sg[8][8];
  build_oct_tables(threadIdx.x, Is, Sg);
  int g4 = blockIdx.x * 256 + threadIdx.x;
  int d0 = (g4 & 255) * 4;
  int s  = g4 >> 8;
  int j = s >> 8, n = s & 255;
  int k = d0 >> 7;
  int i = Is[j][k]; float sg = Sg[j][k];
  const float* wc = WC + (size_t)i * 32768 + n;
  float4 v;
  v.x = sg * wc[(size_t)((d0 + 0) & 127) * 256];
  v.y = sg * wc[(size_t)((d0 + 1) & 127) * 256];
  v.z = sg * wc[(size_t)((d0 + 2) & 127) * 256];
  v.w = sg * wc[(size_t)((d0 + 3) & 127) * 256];
  *(float4*)(CfT + (size_t)g4 * 4) = v;
}

// hx word layout: idx = chunk*64 + pair*8 + b ; word = {pk(hi32) | tag(lo32)}
// chunk c holds s = c*16 .. c*16+15; pair = (s&15)>>1; pk = bf16(h[s_even]) | bf16(h[s_even+1])<<16
__global__ __launch_bounds__(256) void init_h(const float* __restrict__ h_prev, unsigned long long* __restrict__ hx) {
  int gid = blockIdx.x * 256 + threadIdx.x;  // 0..16383
  if (gid < 8192) {
    int c = gid >> 6, within = gid & 63;
    int pr = within >> 3, b = within & 7;
    int s = c * 16 + pr * 2;
    unsigned pk = (unsigned)bf16r(h_prev[(size_t)b * 2048 + s])
                | ((unsigned)bf16r(h_prev[(size_t)b * 2048 + s + 1]) << 16);
    hx[gid] = ((unsigned long long)pk << 32) | 0ull;        // tag 0
  } else {
    hx[gid] = 0x00000000FFFFFFFFull;                        // buf1 sentinel tag
  }
}

// C = X[8192x1024] * Gcat[1024x4096]; cols<2048 -> sigmoid(+bias) -> delta[t][b][s]; else Bx[t][b][s]
__global__ __launch_bounds__(256) void gemm_dbx(const float* __restrict__ X, const float* __restrict__ G,
                                                const float* __restrict__ bias,
                                                float* __restrict__ dlt, float* __restrict__ Bx) {
  __shared__ float As[16][128];
  __shared__ float Bs[16][128];
  const int bn = blockIdx.x, bm = blockIdx.y;
  const int tid = threadIdx.x;
  const int tx = tid & 15, ty = tid >> 4;
  float acc[8][8] = {};
  for (int kt = 0; kt < 1024; kt += 16) {
    #pragma unroll
    for (int q = 0; q < 2; ++q) {
      int slot = tid * 2 + q;
      int r = slot >> 2, c4 = slot & 3;
      float4 v = *(const float4*)(X + (size_t)(bm * 128 + r) * 1024 + kt + c4 * 4);
      As[c4 * 4 + 0][r] = v.x; As[c4 * 4 + 1][r] = v.y;
      As[c4 * 4 + 2][r] = v.z; As[c4 * 4 + 3][r] = v.w;
    }
    #pragma unroll
    for (int q = 0; q < 2; ++q) {
      int slot = tid * 2 + q;
      int kr = slot >> 5, c4 = slot & 31;
      *(float4*)(&Bs[kr][c4 * 4]) = *(const float4*)(G + (size_t)(kt + kr) * 4096 + bn * 128 + c4 * 4);
    }
    __syncthreads();
    #pragma unroll
    for (int kk = 0; kk < 16; ++kk) {
      float a[8], b[8];
      #pragma unroll
      for (int i = 0; i < 8; ++i) a[i] = As[kk][ty + i * 16];
      #pragma unroll
      for (int j = 0; j < 8; ++j) b[j] = Bs[kk][tx + j * 16];
      #pragma unroll
      for (int i = 0; i < 8; ++i)
        #pragma unroll
        for (int j = 0; j < 8; ++j)
          acc[i][j] = fmaf(a[i], b[j], acc[i][j]);
    }
    __syncthreads();
  }
  const bool isDelta = (bn < 16);
  #pragma unroll
  for (int i = 0; i < 8; ++i) {
    int r = bm * 128 + ty + i * 16;
    int t = r & 1023, b = r >> 10;
    size_t base = ((size_t)t * 8 + b) * 2048;
    #pragma unroll
    for (int j = 0; j < 8; ++j) {
      int n = bn * 128 + tx + j * 16;
      float v = acc[i][j];
      if (isDelta) {
        v += bias[n];
        v = 1.0f / (1.0f + expf(-v));
        dlt[base + n] = v;
      } else {
        Bx[base + (n - 2048)] = v;
      }
    }
  }
}

// y[b][t][d] = sum_s hs[t*8+b][s] * CfT[s][d]
__global__ __launch_bounds__(256) void gemm_y(const float* __restrict__ HS, const float* __restrict__ CfT,
                                              float* __restrict__ out) {
  __shared__ float As[16][128];
  __shared__ float Bs[16][128];
  const int bn = blockIdx.x, bm = blockIdx.y;
  const int tid = threadIdx.x;
  const int tx = tid & 15, ty = tid >> 4;
  float acc[8][8] = {};
  for (int kt = 0; kt < 2048; kt += 16) {
    #pragma unroll
    for (int q = 0; q < 2; ++q) {
      int slot = tid * 2 + q;
      int r = slot >> 2, c4 = slot & 3;
      int rg = bm * 128 + r;
      const float* arow = HS + (size_t)((rg & 1023) * 8 + (rg >> 10)) * 2048;
      float4 v = *(const float4*)(arow + kt + c4 * 4);
      As[c4 * 4 + 0][r] = v.x; As[c4 * 4 + 1][r] = v.y;
      As[c4 * 4 + 2][r] = v.z; As[c4 * 4 + 3][r] = v.w;
    }
    #pragma unroll
    for (int q = 0; q < 2; ++q) {
      int slot = tid * 2 + q;
      int kr = slot >> 5, c4 = slot & 31;
      *(float4*)(&Bs[kr][c4 * 4]) = *(const float4*)(CfT + (size_t)(kt + kr) * 1024 + bn * 128 + c4 * 4);
    }
    __syncthreads();
    #pragma unroll
    for (int kk = 0; kk < 16; ++kk) {
      float a[8], b[8];
      #pragma unroll
      for (int i = 0; i < 8; ++i) a[i] = As[kk][ty + i * 16];
      #pragma unroll
      for (int j = 0; j < 8; ++j) b[j] = Bs[kk][tx + j * 16];
      #pragma unroll
      for (int i = 0; i < 8; ++i)
        #pragma unroll
        for (int j = 0; j < 8; ++j)
          acc[i][j] = fmaf(a[i], b[j], acc[i][j]);
    }
    __syncthreads();
  }
  #pragma unroll
  for (int i = 0; i < 8; ++i) {
    size_t rg = bm * 128 + ty + i * 16;
    #pragma unroll
    for (int j = 0; j < 8; ++j) {
      int n = bn * 128 + tx + j * 16;
      out[rg * 1024 + n] = acc[i][j];
    }
  }
}

// Persistent scan: 128 WGs x 512 threads, WG owns 16 sp rows. A-frags in registers (bf16).
// Exchange: self-tagged u64 words {bf16 pair | tag32}, fire-and-forget publish, stale-only re-load.
__global__ __launch_bounds__(512) void scan_kernel(const float* __restrict__ AfM, const float* __restrict__ dlt,
                                                   const float* __restrict__ Bx, float* __restrict__ hs,
                                                   unsigned long long* __restrict__ hx,
                                                   const float* __restrict__ h_prev, float* __restrict__ hlast) {
  __shared__ float red[8 * 144];           // [wave][m(16) pitch 9] -> conflict-light
  const int wg = blockIdx.x;               // 0..127
  const int tid = threadIdx.x;
  const int lane = tid & 63;
  const int w = tid >> 6;                  // wave 0..7 (K-slice of 256)
  const int row = lane & 15;               // A m-row (sp_local) / D col n
  const int g4 = lane >> 4;                // k-group 0..3
  const int nb = lane & 7;                 // batch (cols 8..15 duplicate)

  // A-frags: afr[q] = Af[wg*16+row][w*256 + q*32 + g4*8 .. +7] in bf16
  short8 afr[8];
  {
    const float* base = AfM + (size_t)(wg * 16 + row) * 2048 + w * 256 + g4 * 8;
    #pragma unroll
    for (int q = 0; q < 8; ++q) {
      float4 f0 = *(const float4*)(base + q * 32);
      float4 f1 = *(const float4*)(base + q * 32 + 4);
      short8 v;
      v[0] = (short)bf16r(f0.x); v[1] = (short)bf16r(f0.y);
      v[2] = (short)bf16r(f0.z); v[3] = (short)bf16r(f0.w);
      v[4] = (short)bf16r(f1.x); v[5] = (short)bf16r(f1.y);
      v[6] = (short)bf16r(f1.z); v[7] = (short)bf16r(f1.w);
      afr[q] = v;
    }
  }
  // consumer u64 base: word(q,r) = ubase + q*128 + r*8
  const int ubase = w * 1024 + (g4 >> 1) * 64 + (g4 & 1) * 32 + nb;

  // producer lanes (wave 0): ub = batch, usp = sp pair base
  const int ub = tid >> 3, usp = (tid & 7) * 2;
  const int pword = wg * 64 + (tid & 7) * 8 + ub;
  float hr0 = 0.f, hr1 = 0.f;
  if (tid < 64) {
    hr0 = h_prev[(size_t)ub * 2048 + wg * 16 + usp];
    hr1 = h_prev[(size_t)ub * 2048 + wg * 16 + usp + 1];
  }

  #pragma unroll 1
  for (int t = 0; t < T_STEPS; ++t) {
    float2 dv = make_float2(0.f, 0.f), bxv = make_float2(0.f, 0.f);
    if (tid < 64) {
      size_t off = ((size_t)t * 8 + ub) * 2048 + wg * 16 + usp;
      dv  = *(const float2*)(dlt + off);
      bxv = *(const float2*)(Bx + off);
    }
    const unsigned want = (unsigned)t;
    const unsigned long long* bq = hx + (size_t)(t & 1) * 8192;
    unsigned long long wv[32];
    #pragma unroll
    for (int j = 0; j < 32; ++j)
      wv[j] = __hip_atomic_load(bq + ubase + (j >> 2) * 128 + (j & 3) * 8,
                                __ATOMIC_RELAXED, __HIP_MEMORY_SCOPE_SYSTEM);
    for (;;) {
      bool stale = false;
      #pragma unroll
      for (int j = 0; j < 32; ++j) stale |= ((unsigned)wv[j] != want);
      if (!__any(stale)) break;
      #pragma unroll
      for (int j = 0; j < 32; ++j)
        if ((unsigned)wv[j] != want)
          wv[j] = __hip_atomic_load(bq + ubase + (j >> 2) * 128 + (j & 3) * 8,
                                    __ATOMIC_RELAXED, __HIP_MEMORY_SCOPE_SYSTEM);
    }
    f32x4 acc = {0.f, 0.f, 0.f, 0.f};
    #pragma unroll
    for (int q = 0; q < 8; ++q) {
      union { unsigned d[4]; short8 v; } bb;
      bb.d[0] = (unsigned)(wv[q * 4 + 0] >> 32);
      bb.d[1] = (unsigned)(wv[q * 4 + 1] >> 32);
      bb.d[2] = (unsigned)(wv[q * 4 + 2] >> 32);
      bb.d[3] = (unsigned)(wv[q * 4 + 3] >> 32);
      acc = __builtin_amdgcn_mfma_f32_16x16x32_bf16(afr[q], bb.v, acc, 0, 0, 0);
    }
    // partial D -> LDS; D element (m = g4*4+r, n = row), valid n<8
    if (row < 8) {
      #pragma unroll
      for (int r = 0; r < 4; ++r)
        red[w * 144 + (g4 * 4 + r) * 9 + row] = acc[r];
    }
    __syncthreads();
    if (tid < 64) {
      float o0 = 0.f, o1 = 0.f;
      #pragma unroll
      for (int ww = 0; ww < 8; ++ww) {
        o0 += red[ww * 144 + usp * 9 + ub];
        o1 += red[ww * 144 + (usp + 1) * 9 + ub];
      }
      float h0 = fmaf(dv.x, o0 + bxv.x - hr0, hr0);
      float h1 = fmaf(dv.y, o1 + bxv.y - hr1, hr1);
      hr0 = h0; hr1 = h1;
      size_t off = ((size_t)t * 8 + ub) * 2048 + wg * 16 + usp;
      *(float2*)(hs + off) = make_float2(h0, h1);
      unsigned pk = (unsigned)bf16r(h0) | ((unsigned)bf16r(h1) << 16);
      unsigned long long wval = ((unsigned long long)pk << 32) | (unsigned long long)(unsigned)(t + 1);
      __hip_atomic_store(hx + (size_t)((t + 1) & 1) * 8192 + pword, wval,
                         __ATOMIC_RELAXED, __HIP_MEMORY_SCOPE_SYSTEM);
      if (t == T_STEPS - 1)
        *(float2*)(hlast + (size_t)ub * 2048 + wg * 16 + usp) = make_float2(h0, h1);
    }
    __syncthreads();  // red reusable next step
  }
}

extern "C" void kernel_launch(void* const* d_in, const int* in_sizes, int n_in,
                              void* d_out, int out_size, void* d_ws, size_t ws_size,
                              hipStream_t stream) {
  const float* x      = (const float*)d_in[0];
  const float* h_prev = (const float*)d_in[1];
  const float* WA     = (const float*)d_in[2];
  const float* WB     = (const float*)d_in[3];
  const float* WC     = (const float*)d_in[4];
  const float* Wd     = (const float*)d_in[5];
  const float* bias   = (const float*)d_in[6];
  float* out = (float*)d_out;
  float* w = (float*)d_ws;
  float* AfM  = w + OFF_AFT;
  float* Gcat = w + OFF_GCAT;
  float* CfT  = w + OFF_CFT;
  float* dlt  = w + OFF_DELTA;
  float* Bx   = w + OFF_BX;
  float* hs   = w + OFF_HS;
  unsigned long long* hx = (unsigned long long*)(w + OFF_HBUF);

  fold_A <<<4096, 256, 0, stream>>>(WA, AfM);
  fold_GC<<<4096, 256, 0, stream>>>(Wd, WB, Gcat);
  fold_C <<<2048, 256, 0, stream>>>(WC, CfT);
  init_h <<<64,   256, 0, stream>>>(h_prev, hx);
  gemm_dbx<<<dim3(32, 64), 256, 0, stream>>>(x, Gcat, bias, dlt, Bx);
  scan_kernel<<<128, 512, 0, stream>>>(AfM, dlt, Bx, hs, hx, h_prev, out + 8388608);
  gemm_y<<<dim3(8, 64), 256, 0, stream>>>(hs, CfT, out);
}